// Round 2
// baseline (358.034 us; speedup 1.0000x reference)
//
#include <hip/hip_runtime.h>
#include <cstdint>
#include <cstddef>

#define NN 8192
#define DD 256

typedef __bf16 bf16x8 __attribute__((ext_vector_type(8)));
typedef float f32x4 __attribute__((ext_vector_type(4)));

// ---------------- prep: fp32 -> bf16 (RNE) + row sum-of-squares ----------------
__global__ __launch_bounds__(256) void prep_kernel(const float* __restrict__ x,
                                                   unsigned short* __restrict__ xb,
                                                   float* __restrict__ sq) {
    const int row = blockIdx.x;
    const int c = threadIdx.x;           // 256 threads = D columns
    const size_t idx = (size_t)row * DD + c;
    const float v = x[idx];
    unsigned int u = __float_as_uint(v);
    unsigned int r = (u + 0x7FFFu + ((u >> 16) & 1u)) >> 16;   // RNE fp32->bf16
    xb[idx] = (unsigned short)r;

    float p = v * v;
#pragma unroll
    for (int off = 32; off > 0; off >>= 1) p += __shfl_down(p, off, 64);
    __shared__ float wsum[4];
    const int wave = c >> 6, lane = c & 63;
    if (lane == 0) wsum[wave] = p;
    __syncthreads();
    if (c == 0) sq[row] = wsum[0] + wsum[1] + wsum[2] + wsum[3];
}

// ---------------- symmetric GEMM (X · X^T) + fused sigmoid-distance epilogue ----
// Upper-triangle block tiles only (2080 of 4096); each tile written direct +
// transposed mirror (LDS-bounced for coalescing). m97 structure otherwise:
// 128x128 tile, 4 waves 2x2, 64x64/wave, 16x16x32 bf16 MFMA, BK=32,
// global_load_lds width=16.
__global__ __launch_bounds__(256) void gemm_sig_kernel(
    const unsigned short* __restrict__ Xb, const float* __restrict__ sq,
    const float* __restrict__ thrp, const float* __restrict__ tp,
    float* __restrict__ out) {
    __shared__ __align__(16) unsigned short lA[128 * 32];
    __shared__ __align__(16) unsigned short lB[128 * 32];
    __shared__ float tbuf[4][16 * 65];   // per-wave 16x64 slab, stride 65 (pad)

    const int tid = threadIdx.x;
    const int wave = tid >> 6;
    const int lane = tid & 63;

    // linear block id -> upper-triangle (brow <= bcol): id = bcol*(bcol+1)/2 + brow
    {
    }
    const int b = blockIdx.x;
    int i = (int)((sqrtf(8.0f * (float)b + 1.0f) - 1.0f) * 0.5f);
    while ((i + 1) * (i + 2) / 2 <= b) ++i;
    while (i * (i + 1) / 2 > b) --i;
    const int bcol = i;
    const int brow = b - i * (i + 1) / 2;   // brow <= bcol
    const bool diag = (brow == bcol);

    const int wrow = (wave >> 1) * 64;
    const int wcol = (wave & 1) * 64;

    // staging: chunk = 16 rows of [128][32]; lane l -> row chunk*16 + l/4,
    // k-octet (l&3)*8 -> LDS contiguous in lane order (global_load_lds rule).
    const int srow = lane >> 2;
    const int scol = (lane & 3) * 8;

    const size_t rowA0 = (size_t)brow * 128;
    const size_t rowB0 = (size_t)bcol * 128;

    f32x4 acc[4][4] = {};

    const int fr = lane & 15;            // A/B operand: m = lane&15
    const int fk = (lane >> 4) * 8;      // k-octet = (lane>>4)*8

    for (int k0 = 0; k0 < DD; k0 += 32) {
        __syncthreads();
#pragma unroll
        for (int r = 0; r < 2; ++r) {
            const int chunk = wave * 2 + r;
            const int row = chunk * 16 + srow;
            const unsigned short* gA = Xb + (rowA0 + row) * DD + (k0 + scol);
            const unsigned short* gB = Xb + (rowB0 + row) * DD + (k0 + scol);
            __builtin_amdgcn_global_load_lds(
                (const __attribute__((address_space(1))) void*)gA,
                (__attribute__((address_space(3))) void*)(&lA[chunk * 512]), 16, 0, 0);
            __builtin_amdgcn_global_load_lds(
                (const __attribute__((address_space(1))) void*)gB,
                (__attribute__((address_space(3))) void*)(&lB[chunk * 512]), 16, 0, 0);
        }
        __syncthreads();

        bf16x8 af[4], bfv[4];
#pragma unroll
        for (int t = 0; t < 4; ++t) {
            af[t]  = *(const bf16x8*)&lA[(wrow + t * 16 + fr) * 32 + fk];
            bfv[t] = *(const bf16x8*)&lB[(wcol + t * 16 + fr) * 32 + fk];
        }
#pragma unroll
        for (int ti = 0; ti < 4; ++ti)
#pragma unroll
            for (int tj = 0; tj < 4; ++tj)
                acc[ti][tj] = __builtin_amdgcn_mfma_f32_16x16x32_bf16(
                    af[ti], bfv[tj], acc[ti][tj], 0, 0, 0);
    }

    // epilogue: dist2 = sq_i + sq_j - 2*dot; diag forced 0; v = sigmoid(-(dist+thr)*t)
    const float thr = thrp[0];
    const float tv = tp[0];
    const int c0 = lane & 15;            // C/D: col = lane&15
    const int r0 = (lane >> 4) * 4;      //      row = (lane>>4)*4 + reg
    float* twb = &tbuf[wave][0];

#pragma unroll
    for (int ti = 0; ti < 4; ++ti) {
#pragma unroll
        for (int tj = 0; tj < 4; ++tj) {
            const size_t gcol = rowB0 + wcol + tj * 16 + c0;
            const float sqj = sq[gcol];
            const size_t growb = rowA0 + wrow + ti * 16 + r0;
#pragma unroll
            for (int rg = 0; rg < 4; ++rg) {
                const size_t grow = growb + rg;
                float d2 = sq[grow] + sqj - 2.0f * acc[ti][tj][rg];
                if (grow == gcol) d2 = 0.0f;   // kill bf16 cancellation on diagonal
                d2 = fmaxf(d2, 1e-12f);
                const float dist = sqrtf(d2);
                const float diff = (dist + thr) * tv;
                const float v = 1.0f / (1.0f + __expf(diff));
                out[grow * NN + gcol] = v;
                if (!diag) twb[(r0 + rg) * 65 + tj * 16 + c0] = v;  // wave-local slab
            }
        }
        if (!diag) {
            // wave-local LDS transpose -> coalesced mirror store (no barrier:
            // each wave owns its tbuf slab; compiler inserts lgkmcnt waits).
            const size_t colbase = rowA0 + wrow + ti * 16;   // 16 mirror cols
            const int rloc = lane & 15;          // mirror col offset (contig/quarter)
            const int cq = lane >> 4;            // mirror row sub-offset
#pragma unroll
            for (int i2 = 0; i2 < 16; ++i2) {
                const int cloc = i2 * 4 + cq;    // 0..63 local output row in slab
                const float v = twb[rloc * 65 + cloc];
                out[(rowB0 + wcol + cloc) * NN + colbase + rloc] = v;
            }
        }
    }
}

extern "C" void kernel_launch(void* const* d_in, const int* in_sizes, int n_in,
                              void* d_out, int out_size, void* d_ws, size_t ws_size,
                              hipStream_t stream) {
    const float* x = (const float*)d_in[0];
    const float* threshold = (const float*)d_in[1];
    const float* t = (const float*)d_in[2];
    float* out = (float*)d_out;

    unsigned short* xb = (unsigned short*)d_ws;                       // 4 MB bf16 X
    float* sq = (float*)((char*)d_ws + (size_t)NN * DD * sizeof(unsigned short));

    prep_kernel<<<NN, 256, 0, stream>>>(x, xb, sq);
    const int nblocks = (NN / 128) * (NN / 128 + 1) / 2;              // 2080
    gemm_sig_kernel<<<nblocks, 256, 0, stream>>>(xb, sq, threshold, t, out);
}

// Round 3
// 299.414 us; speedup vs baseline: 1.1958x; 1.1958x over previous
//
#include <hip/hip_runtime.h>
#include <cstdint>
#include <cstddef>

#define NN 8192
#define DD 256

typedef __bf16 bf16x8 __attribute__((ext_vector_type(8)));
typedef float f32x4 __attribute__((ext_vector_type(4)));

// ---------------- prep: fp32 -> bf16 (RNE) + row sum-of-squares ----------------
__global__ __launch_bounds__(256) void prep_kernel(const float* __restrict__ x,
                                                   unsigned short* __restrict__ xb,
                                                   float* __restrict__ sq) {
    const int row = blockIdx.x;
    const int c = threadIdx.x;           // 256 threads = D columns
    const size_t idx = (size_t)row * DD + c;
    const float v = x[idx];
    unsigned int u = __float_as_uint(v);
    unsigned int r = (u + 0x7FFFu + ((u >> 16) & 1u)) >> 16;   // RNE fp32->bf16
    xb[idx] = (unsigned short)r;

    float p = v * v;
#pragma unroll
    for (int off = 32; off > 0; off >>= 1) p += __shfl_down(p, off, 64);
    __shared__ float wsum[4];
    const int wave = c >> 6, lane = c & 63;
    if (lane == 0) wsum[wave] = p;
    __syncthreads();
    if (c == 0) sq[row] = wsum[0] + wsum[1] + wsum[2] + wsum[3];
}

// ---------------- GEMM (X · X^T) + fused sigmoid-distance epilogue ----------------
// R1 structure (full 64x64 grid of 128x128 tiles) with VALU-diet:
//  - k-loop fully unrolled; k0 folded into global_load_lds imm offset (0 addr VALU)
//  - epilogue: rcp instead of fp32 divide, raw sqrt, batched sq prefetch,
//    block-uniform diag branch, constant-offset stores.
__global__ __launch_bounds__(256) void gemm_sig_kernel(
    const unsigned short* __restrict__ Xb, const float* __restrict__ sq,
    const float* __restrict__ thrp, const float* __restrict__ tp,
    float* __restrict__ out) {
    __shared__ __align__(16) unsigned short lA[128 * 32];
    __shared__ __align__(16) unsigned short lB[128 * 32];

    const int tid = threadIdx.x;
    const int wave = tid >> 6;
    const int lane = tid & 63;

    const int brow = blockIdx.y;
    const int bcol = blockIdx.x;
    const int wrow = (wave >> 1) * 64;
    const int wcol = (wave & 1) * 64;

    // staging map (m97-proven): chunk = 16 rows of [128][32]; lane l -> row
    // chunk*16 + l/4, k-octet (l&3)*8; LDS contiguous in lane order.
    const int srow = lane >> 2;
    const int scol = (lane & 3) * 8;

    const size_t rowA0 = (size_t)brow * 128;
    const size_t rowB0 = (size_t)bcol * 128;

    // staging base pointers, computed ONCE (k0 goes into the imm offset)
    const unsigned short* gA0 = Xb + (rowA0 + wave * 32 + srow) * DD + scol;
    const unsigned short* gA1 = gA0 + 16 * DD;
    const unsigned short* gB0 = Xb + (rowB0 + wave * 32 + srow) * DD + scol;
    const unsigned short* gB1 = gB0 + 16 * DD;
    unsigned short* ldsA0 = &lA[(wave * 2 + 0) * 512];
    unsigned short* ldsA1 = &lA[(wave * 2 + 1) * 512];
    unsigned short* ldsB0 = &lB[(wave * 2 + 0) * 512];
    unsigned short* ldsB1 = &lB[(wave * 2 + 1) * 512];

    f32x4 acc[4][4] = {};

    const int fr = lane & 15;            // A/B operand: m = lane&15
    const int fk = (lane >> 4) * 8;      // k-octet = (lane>>4)*8

#define KSTEP(KK)                                                                  \
    do {                                                                           \
        __syncthreads();                                                           \
        __builtin_amdgcn_global_load_lds(                                          \
            (const __attribute__((address_space(1))) void*)gA0,                    \
            (__attribute__((address_space(3))) void*)ldsA0, 16, (KK) * 64, 0);     \
        __builtin_amdgcn_global_load_lds(                                          \
            (const __attribute__((address_space(1))) void*)gA1,                    \
            (__attribute__((address_space(3))) void*)ldsA1, 16, (KK) * 64, 0);     \
        __builtin_amdgcn_global_load_lds(                                          \
            (const __attribute__((address_space(1))) void*)gB0,                    \
            (__attribute__((address_space(3))) void*)ldsB0, 16, (KK) * 64, 0);     \
        __builtin_amdgcn_global_load_lds(                                          \
            (const __attribute__((address_space(1))) void*)gB1,                    \
            (__attribute__((address_space(3))) void*)ldsB1, 16, (KK) * 64, 0);     \
        __syncthreads();                                                           \
        bf16x8 af[4], bfv[4];                                                      \
        _Pragma("unroll") for (int t = 0; t < 4; ++t) {                            \
            af[t] = *(const bf16x8*)&lA[(wrow + t * 16 + fr) * 32 + fk];           \
            bfv[t] = *(const bf16x8*)&lB[(wcol + t * 16 + fr) * 32 + fk];          \
        }                                                                          \
        _Pragma("unroll") for (int ti = 0; ti < 4; ++ti)                           \
            _Pragma("unroll") for (int tj = 0; tj < 4; ++tj)                       \
                acc[ti][tj] = __builtin_amdgcn_mfma_f32_16x16x32_bf16(             \
                    af[ti], bfv[tj], acc[ti][tj], 0, 0, 0);                        \
    } while (0)

    KSTEP(0); KSTEP(1); KSTEP(2); KSTEP(3);
    KSTEP(4); KSTEP(5); KSTEP(6); KSTEP(7);
#undef KSTEP

    // ---- epilogue: d2 = sq_i + sq_j - 2*dot; diag forced 0; v = 1/(1+exp((d+thr)*t))
    const float tv = tp[0];
    const float thr_t = thrp[0] * tv;    // diff = dist*t + thr*t  (one fma)
    const int c0 = lane & 15;            // C/D: col = lane&15
    const int r0q = (lane >> 4) * 4;     //      row = (lane>>4)*4 + reg

    float sqi[16], sqj[4];
#pragma unroll
    for (int ti = 0; ti < 4; ++ti)
#pragma unroll
        for (int rg = 0; rg < 4; ++rg)
            sqi[ti * 4 + rg] = sq[rowA0 + wrow + ti * 16 + r0q + rg];
#pragma unroll
    for (int tj = 0; tj < 4; ++tj) sqj[tj] = sq[rowB0 + wcol + tj * 16 + c0];

    float* ob = out + (rowA0 + wrow + r0q) * NN + (rowB0 + wcol + c0);

    if (brow != bcol) {
#pragma unroll
        for (int ti = 0; ti < 4; ++ti)
#pragma unroll
            for (int tj = 0; tj < 4; ++tj)
#pragma unroll
                for (int rg = 0; rg < 4; ++rg) {
                    float d2 = fmaf(-2.0f, acc[ti][tj][rg], sqi[ti * 4 + rg] + sqj[tj]);
                    d2 = fmaxf(d2, 1e-12f);
                    const float dist = __builtin_amdgcn_sqrtf(d2);
                    const float e = __expf(fmaf(dist, tv, thr_t));
                    ob[(size_t)(ti * 16 + rg) * NN + tj * 16] =
                        __builtin_amdgcn_rcpf(1.0f + e);
                }
    } else {
#pragma unroll
        for (int ti = 0; ti < 4; ++ti)
#pragma unroll
            for (int tj = 0; tj < 4; ++tj)
#pragma unroll
                for (int rg = 0; rg < 4; ++rg) {
                    const int rloc = wrow + ti * 16 + r0q + rg;
                    const int cloc = wcol + tj * 16 + c0;
                    float d2 = fmaf(-2.0f, acc[ti][tj][rg], sqi[ti * 4 + rg] + sqj[tj]);
                    if (rloc == cloc) d2 = 0.0f;   // kill bf16 cancellation on diagonal
                    d2 = fmaxf(d2, 1e-12f);
                    const float dist = __builtin_amdgcn_sqrtf(d2);
                    const float e = __expf(fmaf(dist, tv, thr_t));
                    ob[(size_t)(ti * 16 + rg) * NN + tj * 16] =
                        __builtin_amdgcn_rcpf(1.0f + e);
                }
    }
}

extern "C" void kernel_launch(void* const* d_in, const int* in_sizes, int n_in,
                              void* d_out, int out_size, void* d_ws, size_t ws_size,
                              hipStream_t stream) {
    const float* x = (const float*)d_in[0];
    const float* threshold = (const float*)d_in[1];
    const float* t = (const float*)d_in[2];
    float* out = (float*)d_out;

    unsigned short* xb = (unsigned short*)d_ws;                       // 4 MB bf16 X
    float* sq = (float*)((char*)d_ws + (size_t)NN * DD * sizeof(unsigned short));

    prep_kernel<<<NN, 256, 0, stream>>>(x, xb, sq);
    dim3 grid(NN / 128, NN / 128);
    gemm_sig_kernel<<<grid, 256, 0, stream>>>(xb, sq, threshold, t, out);
}

// Round 4
// 299.212 us; speedup vs baseline: 1.1966x; 1.0007x over previous
//
#include <hip/hip_runtime.h>
#include <cstdint>
#include <cstddef>

#define NN 8192
#define DD 256

typedef __bf16 bf16x8 __attribute__((ext_vector_type(8)));
typedef float f32x4 __attribute__((ext_vector_type(4)));
typedef unsigned short ushort8 __attribute__((ext_vector_type(8)));

// ---- prep: fp32 -> bf16 (RNE), TRANSPOSED k-octet-major layout + row sumsq ----
// XbT layout: [32 k-octets][8192 rows][8 bf16]  (so MFMA fragment loads coalesce)
__global__ __launch_bounds__(256) void prep_kernel(const float* __restrict__ x,
                                                   unsigned short* __restrict__ xbt,
                                                   float* __restrict__ sq) {
    const int t = threadIdx.x;
    const int oct = t & 31;                    // k-octet 0..31
    const int rl = t >> 5;                     // 0..7
    const int row = blockIdx.x * 8 + rl;
    const float4* xp = (const float4*)(x + (size_t)row * DD + oct * 8);
    const float4 a = xp[0], b = xp[1];
    const float vs[8] = {a.x, a.y, a.z, a.w, b.x, b.y, b.z, b.w};
    ushort8 o;
    float p = 0.0f;
#pragma unroll
    for (int i = 0; i < 8; ++i) {
        const float v = vs[i];
        const unsigned int u = __float_as_uint(v);
        o[i] = (unsigned short)((u + 0x7FFFu + ((u >> 16) & 1u)) >> 16);  // RNE
        p = fmaf(v, v, p);
    }
    *(ushort8*)(xbt + ((size_t)oct * NN + row) * 8) = o;
    // lanes 0-31 of each half-wave share a row -> width-32 reduction
#pragma unroll
    for (int off = 16; off > 0; off >>= 1) p += __shfl_down(p, off, 32);
    if (oct == 0) sq[row] = p;
}

// ---- no-LDS GEMM (X · X^T) + fused sigmoid-distance epilogue -------------------
// Zero barriers, zero LDS: each wave loads its MFMA fragments directly from the
// k-major XbT (perfectly coalesced dwordx4), register ping-pong 1 kstep ahead.
// Block = 4 waves in 2x2 (128x128 tile) purely for grid bookkeeping.
__global__ __launch_bounds__(256) void gemm_sig_kernel(
    const unsigned short* __restrict__ XbT, const float* __restrict__ sq,
    const float* __restrict__ thrp, const float* __restrict__ tp,
    float* __restrict__ out) {
    const int tid = threadIdx.x;
    const int wave = tid >> 6;
    const int lane = tid & 63;

    const int brow = blockIdx.y;
    const int bcol = blockIdx.x;
    const int wrow = (wave >> 1) * 64;
    const int wcol = (wave & 1) * 64;

    const int fr = lane & 15;                 // fragment row within 16-tile
    const int q = lane >> 4;                  // quarter -> k-octet select

    const size_t rowA0 = (size_t)brow * 128;
    const size_t rowB0 = (size_t)bcol * 128;

    // base pointers (ushort units): ((kk*4 + q)*NN + row)*8
    const unsigned short* pA = XbT + ((size_t)q * NN + rowA0 + wrow + fr) * 8;
    const unsigned short* pB = XbT + ((size_t)q * NN + rowB0 + wcol + fr) * 8;
    const size_t kkStride = (size_t)4 * NN * 8;    // ushorts per kstep

    f32x4 acc[4][4] = {};
    bf16x8 afp[2][4], bfp[2][4];

#pragma unroll
    for (int t = 0; t < 4; ++t) {             // prologue: kstep 0
        afp[0][t] = *(const bf16x8*)(pA + t * 128);
        bfp[0][t] = *(const bf16x8*)(pB + t * 128);
    }
#pragma unroll
    for (int kk = 0; kk < 8; ++kk) {
        const int cur = kk & 1, nxt = cur ^ 1;
        if (kk < 7) {
            const unsigned short* nA = pA + (size_t)(kk + 1) * kkStride;
            const unsigned short* nB = pB + (size_t)(kk + 1) * kkStride;
#pragma unroll
            for (int t = 0; t < 4; ++t) {
                afp[nxt][t] = *(const bf16x8*)(nA + t * 128);
                bfp[nxt][t] = *(const bf16x8*)(nB + t * 128);
            }
        }
#pragma unroll
        for (int ti = 0; ti < 4; ++ti)
#pragma unroll
            for (int tj = 0; tj < 4; ++tj)
                acc[ti][tj] = __builtin_amdgcn_mfma_f32_16x16x32_bf16(
                    afp[cur][ti], bfp[cur][tj], acc[ti][tj], 0, 0, 0);
    }

    // ---- epilogue: d2 = sq_i + sq_j - 2*dot; diag forced 0; v = 1/(1+exp((d+thr)*t))
    const float tv = tp[0];
    const float thr_t = thrp[0] * tv;
    const int c0 = lane & 15;                 // C/D: col = lane&15
    const int r0q = (lane >> 4) * 4;          //      row = (lane>>4)*4 + reg

    float sqi[16], sqj[4];
#pragma unroll
    for (int ti = 0; ti < 4; ++ti)
#pragma unroll
        for (int rg = 0; rg < 4; ++rg)
            sqi[ti * 4 + rg] = sq[rowA0 + wrow + ti * 16 + r0q + rg];
#pragma unroll
    for (int tj = 0; tj < 4; ++tj) sqj[tj] = sq[rowB0 + wcol + tj * 16 + c0];

    float* ob = out + (rowA0 + wrow + r0q) * NN + (rowB0 + wcol + c0);

    if (brow != bcol) {
#pragma unroll
        for (int ti = 0; ti < 4; ++ti)
#pragma unroll
            for (int tj = 0; tj < 4; ++tj)
#pragma unroll
                for (int rg = 0; rg < 4; ++rg) {
                    float d2 = fmaf(-2.0f, acc[ti][tj][rg], sqi[ti * 4 + rg] + sqj[tj]);
                    d2 = fmaxf(d2, 1e-12f);
                    const float dist = __builtin_amdgcn_sqrtf(d2);
                    const float e = __expf(fmaf(dist, tv, thr_t));
                    ob[(size_t)(ti * 16 + rg) * NN + tj * 16] =
                        __builtin_amdgcn_rcpf(1.0f + e);
                }
    } else {
#pragma unroll
        for (int ti = 0; ti < 4; ++ti)
#pragma unroll
            for (int tj = 0; tj < 4; ++tj)
#pragma unroll
                for (int rg = 0; rg < 4; ++rg) {
                    const int rloc = wrow + ti * 16 + r0q + rg;
                    const int cloc = wcol + tj * 16 + c0;
                    float d2 = fmaf(-2.0f, acc[ti][tj][rg], sqi[ti * 4 + rg] + sqj[tj]);
                    if (rloc == cloc) d2 = 0.0f;   // kill bf16 cancellation on diagonal
                    d2 = fmaxf(d2, 1e-12f);
                    const float dist = __builtin_amdgcn_sqrtf(d2);
                    const float e = __expf(fmaf(dist, tv, thr_t));
                    ob[(size_t)(ti * 16 + rg) * NN + tj * 16] =
                        __builtin_amdgcn_rcpf(1.0f + e);
                }
    }
}

extern "C" void kernel_launch(void* const* d_in, const int* in_sizes, int n_in,
                              void* d_out, int out_size, void* d_ws, size_t ws_size,
                              hipStream_t stream) {
    const float* x = (const float*)d_in[0];
    const float* threshold = (const float*)d_in[1];
    const float* t = (const float*)d_in[2];
    float* out = (float*)d_out;

    unsigned short* xbt = (unsigned short*)d_ws;                      // 4 MB bf16 X^T (k-major)
    float* sq = (float*)((char*)d_ws + (size_t)NN * DD * sizeof(unsigned short));

    prep_kernel<<<NN / 8, 256, 0, stream>>>(x, xbt, sq);
    dim3 grid(NN / 128, NN / 128);
    gemm_sig_kernel<<<grid, 256, 0, stream>>>(xbt, sq, threshold, t, out);
}

// Round 5
// 286.772 us; speedup vs baseline: 1.2485x; 1.0434x over previous
//
#include <hip/hip_runtime.h>
#include <cstdint>
#include <cstddef>

#define NN 8192
#define DD 256

typedef __bf16 bf16x8 __attribute__((ext_vector_type(8)));
typedef float f32x16 __attribute__((ext_vector_type(16)));
typedef unsigned short ushort8 __attribute__((ext_vector_type(8)));

// ---- prep: fp32 -> bf16 (RNE), k-octet-major transposed layout + row sumsq ----
// XbT layout: [32 k-octets][8192 rows][8 bf16]
__global__ __launch_bounds__(256) void prep_kernel(const float* __restrict__ x,
                                                   unsigned short* __restrict__ xbt,
                                                   float* __restrict__ sq) {
    const int t = threadIdx.x;
    const int oct = t & 31;                    // k-octet 0..31
    const int rl = t >> 5;                     // 0..7
    const int row = blockIdx.x * 8 + rl;
    const float4* xp = (const float4*)(x + (size_t)row * DD + oct * 8);
    const float4 a = xp[0], b = xp[1];
    const float vs[8] = {a.x, a.y, a.z, a.w, b.x, b.y, b.z, b.w};
    ushort8 o;
    float p = 0.0f;
#pragma unroll
    for (int i = 0; i < 8; ++i) {
        const float v = vs[i];
        const unsigned int u = __float_as_uint(v);
        o[i] = (unsigned short)((u + 0x7FFFu + ((u >> 16) & 1u)) >> 16);  // RNE
        p = fmaf(v, v, p);
    }
    *(ushort8*)(xbt + ((size_t)oct * NN + row) * 8) = o;
#pragma unroll
    for (int off = 16; off > 0; off >>= 1) p += __shfl_down(p, off, 32);
    if (oct == 0) sq[row] = p;
}

// ---- no-LDS GEMM (X · X^T), 32x32x16 MFMA, occupancy-targeted (<=128 VGPR) ----
// Block 128x128, 4 waves 2x2, wave tile 64x64 = 2x2 of 32x32 MFMA tiles.
// A/B operand: m = lane&31, k-octet = 2*kk + (lane>>5)  (k-major XbT -> coalesced)
// C/D: col = lane&31, row = (reg&3) + 8*(reg>>2) + 4*(lane>>5)
__global__ __launch_bounds__(256, 4) void gemm_sig_kernel(
    const unsigned short* __restrict__ XbT, const float* __restrict__ sq,
    const float* __restrict__ thrp, const float* __restrict__ tp,
    float* __restrict__ out) {
    const int tid = threadIdx.x;
    const int wave = tid >> 6;
    const int lane = tid & 63;
    const int m = lane & 31;
    const int q2 = lane >> 5;

    const int brow = blockIdx.y;
    const int bcol = blockIdx.x;
    const int wrow = (wave >> 1) * 64;
    const int wcol = (wave & 1) * 64;

    const uint32_t rowA0 = (uint32_t)brow * 128;
    const uint32_t rowB0 = (uint32_t)bcol * 128;

    // ushort-element offsets into XbT (fits 32-bit: 2M elements total)
    const uint32_t offA = ((uint32_t)q2 * NN + rowA0 + wrow + m) * 8;
    const uint32_t offB = ((uint32_t)q2 * NN + rowB0 + wcol + m) * 8;
    const uint32_t kkS = 2u * NN * 8;          // ushorts per k16 step (2 octets)

    f32x16 acc[2][2] = {};
    bf16x8 af[2][2], bfv[2][2];

#pragma unroll
    for (int t = 0; t < 2; ++t) {              // prefetch kk = 0 (ti/tj tiles 32 rows apart)
        af[0][t]  = *(const bf16x8*)(XbT + offA + t * 256);
        bfv[0][t] = *(const bf16x8*)(XbT + offB + t * 256);
    }
#pragma unroll
    for (int kk = 0; kk < 16; ++kk) {
        const int cur = kk & 1, nxt = cur ^ 1;
        if (kk < 15) {
            const uint32_t ko = (uint32_t)(kk + 1) * kkS;
#pragma unroll
            for (int t = 0; t < 2; ++t) {
                af[nxt][t]  = *(const bf16x8*)(XbT + offA + ko + t * 256);
                bfv[nxt][t] = *(const bf16x8*)(XbT + offB + ko + t * 256);
            }
        }
#pragma unroll
        for (int ti = 0; ti < 2; ++ti)
#pragma unroll
            for (int tj = 0; tj < 2; ++tj)
                acc[ti][tj] = __builtin_amdgcn_mfma_f32_32x32x16_bf16(
                    af[cur][ti], bfv[cur][tj], acc[ti][tj], 0, 0, 0);
    }

    // ---- epilogue: d2 = sq_i + sq_j - 2*dot; diag forced 0; v = 1/(1+exp((d+thr)*t))
    const float tv = tp[0];
    const float thr_t = thrp[0] * tv;
    const uint32_t colg0 = rowB0 + wcol + m;

#pragma unroll
    for (int ti = 0; ti < 2; ++ti) {
        const uint32_t rbase = rowA0 + wrow + ti * 32 + 4 * q2;
        float sqi[16];
#pragma unroll
        for (int rg = 0; rg < 16; ++rg)
            sqi[rg] = sq[rbase + (rg & 3) + 8 * (rg >> 2)];
#pragma unroll
        for (int tj = 0; tj < 2; ++tj) {
            const uint32_t colg = colg0 + tj * 32;
            const float sqj = sq[colg];
#pragma unroll
            for (int rg = 0; rg < 16; ++rg) {
                const uint32_t r = rbase + (rg & 3) + 8 * (rg >> 2);
                float d2 = fmaf(-2.0f, acc[ti][tj][rg], sqi[rg] + sqj);
                if (r == colg) d2 = 0.0f;       // diagonal: kill bf16 cancellation
                d2 = fmaxf(d2, 1e-12f);
                const float dist = __builtin_amdgcn_sqrtf(d2);
                const float e = __expf(fmaf(dist, tv, thr_t));
                out[(size_t)r * NN + colg] = __builtin_amdgcn_rcpf(1.0f + e);
            }
        }
    }
}

extern "C" void kernel_launch(void* const* d_in, const int* in_sizes, int n_in,
                              void* d_out, int out_size, void* d_ws, size_t ws_size,
                              hipStream_t stream) {
    const float* x = (const float*)d_in[0];
    const float* threshold = (const float*)d_in[1];
    const float* t = (const float*)d_in[2];
    float* out = (float*)d_out;

    unsigned short* xbt = (unsigned short*)d_ws;                      // 4 MB bf16 X^T (k-major)
    float* sq = (float*)((char*)d_ws + (size_t)NN * DD * sizeof(unsigned short));

    prep_kernel<<<NN / 8, 256, 0, stream>>>(x, xbt, sq);
    dim3 grid(NN / 128, NN / 128);
    gemm_sig_kernel<<<grid, 256, 0, stream>>>(xbt, sq, threshold, t, out);
}